// Round 2
// baseline (24.137 us; speedup 1.0000x reference)
//
#include <hip/hip_runtime.h>

// DenseMLPQMatrixDecoder, fused single-kernel version.
// Q depends only on v (site positions never affect the output), so:
//   block b (b = v): thread 0 runs the MLP -> Q -> expm(1000*Q) chain in
//   fp64 (scaling-and-squaring), stores row 0 to LDS; then all 256 threads
//   broadcast that float4 across the S=1024 sites with coalesced stores.

namespace {

constexpr int kA = 4;
constexpr int kD = 8;
constexpr int kW = 16;
constexpr int kV = 1024;
constexpr int kS = 1024;
constexpr int kSquarings = 14;   // 2^14; tau = 1000/16384 ~ 0.061
constexpr int kTaylorOrder = 8;  // (tau*||Q||)^9/9! ~ 1e-14

__global__ __launch_bounds__(256) void fused_kernel(
    const float* __restrict__ emb,
    const float* __restrict__ W0,
    const float* __restrict__ b0,
    const float* __restrict__ W1,
    const float* __restrict__ b1,
    const float* __restrict__ Wout,
    const float* __restrict__ bout,
    float4* __restrict__ out) {
  const int v = blockIdx.x;
  __shared__ float4 sh_row0;

  if (threadIdx.x == 0) {
    // ---- MLP: D -> W -> W -> A*A (ReLU hidden) ----
    float x[kD];
#pragma unroll
    for (int d = 0; d < kD; ++d) x[d] = emb[v * kD + d];

    float h0[kW];
#pragma unroll
    for (int j = 0; j < kW; ++j) {
      float acc = b0[j];
#pragma unroll
      for (int d = 0; d < kD; ++d) acc = fmaf(x[d], W0[d * kW + j], acc);
      h0[j] = fmaxf(acc, 0.0f);
    }

    float h1[kW];
#pragma unroll
    for (int j = 0; j < kW; ++j) {
      float acc = b1[j];
#pragma unroll
      for (int k = 0; k < kW; ++k) acc = fmaf(h0[k], W1[k * kW + j], acc);
      h1[j] = fmaxf(acc, 0.0f);
    }

    float l[kA * kA];
#pragma unroll
    for (int j = 0; j < kA * kA; ++j) {
      float acc = bout[j];
#pragma unroll
      for (int k = 0; k < kW; ++k)
        acc = fmaf(h1[k], Wout[k * (kA * kA) + j], acc);
      l[j] = acc;
    }

    // ---- M = tau*Q; Q = P - I, P = per-row off-diagonal softmax ----
    const double tau = 1000.0 / (double)(1 << kSquarings);
    double M[kA][kA];
#pragma unroll
    for (int i = 0; i < kA; ++i) {
      float m = -3.0e38f;
#pragma unroll
      for (int j = 0; j < kA; ++j)
        if (j != i) m = fmaxf(m, l[i * kA + j]);
      float e[kA];
      float ssum = 0.0f;
#pragma unroll
      for (int j = 0; j < kA; ++j) {
        e[j] = (j == i) ? 0.0f : expf(l[i * kA + j] - m);
        ssum += e[j];
      }
      const float inv = 1.0f / ssum;
#pragma unroll
      for (int j = 0; j < kA; ++j)
        M[i][j] = tau * ((j == i) ? -1.0 : (double)(e[j] * inv));
    }

    // ---- expm: order-8 Taylor (Horner) + 14 squarings, fp64 ----
    double T[kA][kA];
#pragma unroll
    for (int i = 0; i < kA; ++i)
#pragma unroll
      for (int j = 0; j < kA; ++j) T[i][j] = (i == j) ? 1.0 : 0.0;

#pragma unroll
    for (int k = kTaylorOrder; k >= 1; --k) {
      double U[kA][kA];
#pragma unroll
      for (int i = 0; i < kA; ++i)
#pragma unroll
        for (int j = 0; j < kA; ++j) {
          double acc = 0.0;
#pragma unroll
          for (int p = 0; p < kA; ++p) acc = fma(M[i][p], T[p][j], acc);
          U[i][j] = acc;
        }
      const double rk = 1.0 / (double)k;
#pragma unroll
      for (int i = 0; i < kA; ++i)
#pragma unroll
        for (int j = 0; j < kA; ++j)
          T[i][j] = ((i == j) ? 1.0 : 0.0) + U[i][j] * rk;
    }

#pragma unroll 1
    for (int t = 0; t < kSquarings; ++t) {
      double U[kA][kA];
#pragma unroll
      for (int i = 0; i < kA; ++i)
#pragma unroll
        for (int j = 0; j < kA; ++j) {
          double acc = 0.0;
#pragma unroll
          for (int p = 0; p < kA; ++p) acc = fma(T[i][p], T[p][j], acc);
          U[i][j] = acc;
        }
#pragma unroll
      for (int i = 0; i < kA; ++i)
#pragma unroll
        for (int j = 0; j < kA; ++j) T[i][j] = U[i][j];
    }

    sh_row0 = make_float4((float)T[0][0], (float)T[0][1],
                          (float)T[0][2], (float)T[0][3]);
  }

  __syncthreads();

  const float4 r = sh_row0;
  float4* o = out + (size_t)v * kS;
#pragma unroll
  for (int k = 0; k < kS / 256; ++k) o[k * 256 + threadIdx.x] = r;
}

}  // namespace

extern "C" void kernel_launch(void* const* d_in, const int* in_sizes, int n_in,
                              void* d_out, int out_size, void* d_ws,
                              size_t ws_size, hipStream_t stream) {
  const float* emb  = (const float*)d_in[0];
  // d_in[1] = site_positions_SxC: unused (output is independent of positions)
  const float* W0   = (const float*)d_in[2];
  const float* b0   = (const float*)d_in[3];
  const float* W1   = (const float*)d_in[4];
  const float* b1   = (const float*)d_in[5];
  const float* Wout = (const float*)d_in[6];
  const float* bout = (const float*)d_in[7];

  fused_kernel<<<kV, 256, 0, stream>>>(emb, W0, b0, W1, b1, Wout, bout,
                                       (float4*)d_out);
}

// Round 3
// 15.409 us; speedup vs baseline: 1.5664x; 1.5664x over previous
//
#include <hip/hip_runtime.h>

// DenseMLPQMatrixDecoder, single fused kernel, wave-redundant expm.
// Q depends only on v (site positions never affect the output).
// Grid: 1024 blocks (one per v) x 64 threads (one wave). All 64 lanes
// redundantly compute the MLP -> Q -> expm(1000*Q) chain for this block's v
// (redundant lanes are free: the wave issues the same instructions for 1
// active lane or 64). Result (row 0) ends up in every lane's registers; the
// wave then writes the S=1024 float4 broadcast with 16 coalesced stores/lane.
// No LDS, no barriers, no divergence.

namespace {

constexpr int kA = 4;
constexpr int kD = 8;
constexpr int kW = 16;
constexpr int kV = 1024;
constexpr int kS = 1024;
constexpr int kSquarings = 14;   // 2^14; tau = 1000/16384 ~ 0.061
constexpr int kTaylorOrder = 8;  // (tau*||Q||)^9/9! ~ 1e-14

__global__ __launch_bounds__(64) void fused_kernel(
    const float* __restrict__ emb,
    const float* __restrict__ W0,
    const float* __restrict__ b0,
    const float* __restrict__ W1,
    const float* __restrict__ b1,
    const float* __restrict__ Wout,
    const float* __restrict__ bout,
    float4* __restrict__ out) {
  const int v = blockIdx.x;

  // ---- MLP: D -> W -> W -> A*A (ReLU hidden); uniform across lanes ----
  float x[kD];
#pragma unroll
  for (int d = 0; d < kD; ++d) x[d] = emb[v * kD + d];

  float h0[kW];
#pragma unroll
  for (int j = 0; j < kW; ++j) {
    float acc = b0[j];
#pragma unroll
    for (int d = 0; d < kD; ++d) acc = fmaf(x[d], W0[d * kW + j], acc);
    h0[j] = fmaxf(acc, 0.0f);
  }

  float h1[kW];
#pragma unroll
  for (int j = 0; j < kW; ++j) {
    float acc = b1[j];
#pragma unroll
    for (int k = 0; k < kW; ++k) acc = fmaf(h0[k], W1[k * kW + j], acc);
    h1[j] = fmaxf(acc, 0.0f);
  }

  float l[kA * kA];
#pragma unroll
  for (int j = 0; j < kA * kA; ++j) {
    float acc = bout[j];
#pragma unroll
    for (int k = 0; k < kW; ++k)
      acc = fmaf(h1[k], Wout[k * (kA * kA) + j], acc);
    l[j] = acc;
  }

  // ---- M = tau*Q; Q = P - I, P = per-row off-diagonal softmax ----
  const double tau = 1000.0 / (double)(1 << kSquarings);
  double M[kA][kA];
#pragma unroll
  for (int i = 0; i < kA; ++i) {
    float m = -3.0e38f;
#pragma unroll
    for (int j = 0; j < kA; ++j)
      if (j != i) m = fmaxf(m, l[i * kA + j]);
    float e[kA];
    float ssum = 0.0f;
#pragma unroll
    for (int j = 0; j < kA; ++j) {
      e[j] = (j == i) ? 0.0f : expf(l[i * kA + j] - m);
      ssum += e[j];
    }
    const float inv = 1.0f / ssum;
#pragma unroll
    for (int j = 0; j < kA; ++j)
      M[i][j] = tau * ((j == i) ? -1.0 : (double)(e[j] * inv));
  }

  // ---- expm: order-8 Taylor (Horner) + squarings, fp64 ----
  double T[kA][kA];
#pragma unroll
  for (int i = 0; i < kA; ++i)
#pragma unroll
    for (int j = 0; j < kA; ++j) T[i][j] = (i == j) ? 1.0 : 0.0;

#pragma unroll
  for (int k = kTaylorOrder; k >= 1; --k) {
    double U[kA][kA];
#pragma unroll
    for (int i = 0; i < kA; ++i)
#pragma unroll
      for (int j = 0; j < kA; ++j) {
        double acc = 0.0;
#pragma unroll
        for (int p = 0; p < kA; ++p) acc = fma(M[i][p], T[p][j], acc);
        U[i][j] = acc;
      }
    const double rk = 1.0 / (double)k;
#pragma unroll
    for (int i = 0; i < kA; ++i)
#pragma unroll
      for (int j = 0; j < kA; ++j)
        T[i][j] = ((i == j) ? 1.0 : 0.0) + U[i][j] * rk;
  }

  // 13 full matrix squarings...
#pragma unroll
  for (int t = 0; t < kSquarings - 1; ++t) {
    double U[kA][kA];
#pragma unroll
    for (int i = 0; i < kA; ++i)
#pragma unroll
      for (int j = 0; j < kA; ++j) {
        double acc = 0.0;
#pragma unroll
        for (int p = 0; p < kA; ++p) acc = fma(T[i][p], T[p][j], acc);
        U[i][j] = acc;
      }
#pragma unroll
    for (int i = 0; i < kA; ++i)
#pragma unroll
      for (int j = 0; j < kA; ++j) T[i][j] = U[i][j];
  }

  // ...and the last one only needs row 0: row0(T^2) = row0(T) * T.
  double r0[kA];
#pragma unroll
  for (int j = 0; j < kA; ++j) {
    double acc = 0.0;
#pragma unroll
    for (int p = 0; p < kA; ++p) acc = fma(T[0][p], T[p][j], acc);
    r0[j] = acc;
  }

  const float4 r =
      make_float4((float)r0[0], (float)r0[1], (float)r0[2], (float)r0[3]);

  // ---- broadcast across S sites: 16 coalesced float4 stores per lane ----
  float4* o = out + (size_t)v * kS;
#pragma unroll
  for (int k = 0; k < kS / 64; ++k) o[k * 64 + threadIdx.x] = r;
}

}  // namespace

extern "C" void kernel_launch(void* const* d_in, const int* in_sizes, int n_in,
                              void* d_out, int out_size, void* d_ws,
                              size_t ws_size, hipStream_t stream) {
  const float* emb  = (const float*)d_in[0];
  // d_in[1] = site_positions_SxC: unused (output is independent of positions)
  const float* W0   = (const float*)d_in[2];
  const float* b0   = (const float*)d_in[3];
  const float* W1   = (const float*)d_in[4];
  const float* b1   = (const float*)d_in[5];
  const float* Wout = (const float*)d_in[6];
  const float* bout = (const float*)d_in[7];

  fused_kernel<<<kV, 64, 0, stream>>>(emb, W0, b0, W1, b1, Wout, bout,
                                      (float4*)d_out);
}

// Round 4
// 13.034 us; speedup vs baseline: 1.8519x; 1.1822x over previous
//
#include <hip/hip_runtime.h>
#include <math.h>

// DenseMLPQMatrixDecoder, fused single kernel.
// Q depends only on v; expm(1000*Q) is (to machine precision) the stationary
// distribution pi of the CTMC whenever the spectral gap |Re mu_max| >> 1/1000.
// Fast path: pi via Markov-tree theorem (diagonal 3x3 cofactors of Q, fp64).
// Gate: mu_max from the closed-form cubic (char poly has root 0, tr Q = -4);
// fall back to fp64 scaling-and-squaring expm iff 1000*mu_max > -30.
// Then all 64 lanes broadcast the float4 across S=1024 sites.

namespace {

constexpr int kA = 4;
constexpr int kD = 8;
constexpr int kW = 16;
constexpr int kV = 1024;
constexpr int kS = 1024;
constexpr int kSquarings = 14;   // fallback: 2^14; tau = 1000/16384
constexpr int kTaylorOrder = 8;

__device__ inline double det3(double m00, double m01, double m02,
                              double m10, double m11, double m12,
                              double m20, double m21, double m22) {
  return m00 * (m11 * m22 - m12 * m21) -
         m01 * (m10 * m22 - m12 * m20) +
         m02 * (m10 * m21 - m11 * m20);
}

__global__ __launch_bounds__(64) void fused_kernel(
    const float* __restrict__ emb,
    const float* __restrict__ W0,
    const float* __restrict__ b0,
    const float* __restrict__ W1,
    const float* __restrict__ b1,
    const float* __restrict__ Wout,
    const float* __restrict__ bout,
    float4* __restrict__ out) {
  const int v = blockIdx.x;

  // ---- MLP: D -> W -> W -> A*A (ReLU hidden); uniform across lanes ----
  float x[kD];
#pragma unroll
  for (int d = 0; d < kD; ++d) x[d] = emb[v * kD + d];

  float h0[kW];
#pragma unroll
  for (int j = 0; j < kW; ++j) {
    float acc = b0[j];
#pragma unroll
    for (int d = 0; d < kD; ++d) acc = fmaf(x[d], W0[d * kW + j], acc);
    h0[j] = fmaxf(acc, 0.0f);
  }

  float h1[kW];
#pragma unroll
  for (int j = 0; j < kW; ++j) {
    float acc = b1[j];
#pragma unroll
    for (int k = 0; k < kW; ++k) acc = fmaf(h0[k], W1[k * kW + j], acc);
    h1[j] = fmaxf(acc, 0.0f);
  }

  float l[kA * kA];
#pragma unroll
  for (int j = 0; j < kA * kA; ++j) {
    float acc = bout[j];
#pragma unroll
    for (int k = 0; k < kW; ++k)
      acc = fmaf(h1[k], Wout[k * (kA * kA) + j], acc);
    l[j] = acc;
  }

  // ---- Q = P - I; P = per-row off-diagonal softmax (fp64 entries) ----
  double Q[kA][kA];
#pragma unroll
  for (int i = 0; i < kA; ++i) {
    float m = -3.0e38f;
#pragma unroll
    for (int j = 0; j < kA; ++j)
      if (j != i) m = fmaxf(m, l[i * kA + j]);
    float e[kA];
    float ssum = 0.0f;
#pragma unroll
    for (int j = 0; j < kA; ++j) {
      e[j] = (j == i) ? 0.0f : expf(l[i * kA + j] - m);
      ssum += e[j];
    }
    const float inv = 1.0f / ssum;
#pragma unroll
    for (int j = 0; j < kA; ++j)
      Q[i][j] = (j == i) ? -1.0 : (double)(e[j] * inv);
  }

  // ---- spectral-gap gate: mu_max of the nonzero eigenvalues ----
  // char poly: roots {0, mu_1..3}; sum mu = tr Q = -4 exactly.
  double p2 = 0.0;  // tr(Q^2)
#pragma unroll
  for (int i = 0; i < kA; ++i)
#pragma unroll
    for (int j = 0; j < kA; ++j) p2 = fma(Q[i][j], Q[j][i], p2);

  double Q2[kA][kA];
#pragma unroll
  for (int i = 0; i < kA; ++i)
#pragma unroll
    for (int j = 0; j < kA; ++j) {
      double acc = 0.0;
#pragma unroll
      for (int p = 0; p < kA; ++p) acc = fma(Q[i][p], Q[p][j], acc);
      Q2[i][j] = acc;
    }
  double p3 = 0.0;  // tr(Q^3)
#pragma unroll
  for (int i = 0; i < kA; ++i)
#pragma unroll
    for (int j = 0; j < kA; ++j) p3 = fma(Q2[i][j], Q[j][i], p3);

  const double e2 = (16.0 - p2) * 0.5;
  const double e3 = (-64.0 + 12.0 * p2 + 2.0 * p3) * (1.0 / 6.0);
  // cubic mu^3 + 4 mu^2 + e2 mu - e3 = 0; depressed mu = y - 4/3
  const double pc = e2 - 16.0 / 3.0;
  const double qc = 128.0 / 27.0 - (4.0 / 3.0) * e2 - e3;
  const double disc = 0.25 * qc * qc + (pc * pc * pc) * (1.0 / 27.0);
  double ymax;
  if (disc > 0.0) {  // one real root + complex pair (real part -y1/2)
    const double sd = sqrt(disc);
    const double y1 = cbrt(-0.5 * qc + sd) + cbrt(-0.5 * qc - sd);
    ymax = fmax(y1, -0.5 * y1);
  } else {  // three real roots
    const double r = sqrt(fmax(-pc * (1.0 / 3.0), 0.0));
    double ca = 0.0;
    if (r > 0.0) ca = (-0.5 * qc) / (r * r * r);
    ca = fmin(fmax(ca, -1.0), 1.0);
    ymax = 2.0 * r * cos(acos(ca) * (1.0 / 3.0));
  }
  const double mu_max = ymax - 4.0 / 3.0;

  float4 rvec;
  if (mu_max < -0.03) {
    // ---- fast path: stationary pi via diagonal cofactors (tree theorem) ----
    double c0 = det3(Q[1][1], Q[1][2], Q[1][3],
                     Q[2][1], Q[2][2], Q[2][3],
                     Q[3][1], Q[3][2], Q[3][3]);
    double c1 = det3(Q[0][0], Q[0][2], Q[0][3],
                     Q[2][0], Q[2][2], Q[2][3],
                     Q[3][0], Q[3][2], Q[3][3]);
    double c2 = det3(Q[0][0], Q[0][1], Q[0][3],
                     Q[1][0], Q[1][1], Q[1][3],
                     Q[3][0], Q[3][1], Q[3][3]);
    double c3 = det3(Q[0][0], Q[0][1], Q[0][2],
                     Q[1][0], Q[1][1], Q[1][2],
                     Q[2][0], Q[2][1], Q[2][2]);
    const double inv = 1.0 / (c0 + c1 + c2 + c3);
    rvec = make_float4((float)(c0 * inv), (float)(c1 * inv),
                       (float)(c2 * inv), (float)(c3 * inv));
  } else {
    // ---- fallback: fp64 scaling-and-squaring expm(1000*Q) ----
    const double tau = 1000.0 / (double)(1 << kSquarings);
    double M[kA][kA];
#pragma unroll
    for (int i = 0; i < kA; ++i)
#pragma unroll
      for (int j = 0; j < kA; ++j) M[i][j] = tau * Q[i][j];

    double T[kA][kA];
#pragma unroll
    for (int i = 0; i < kA; ++i)
#pragma unroll
      for (int j = 0; j < kA; ++j) T[i][j] = (i == j) ? 1.0 : 0.0;

#pragma unroll 1
    for (int k = kTaylorOrder; k >= 1; --k) {
      double U[kA][kA];
#pragma unroll
      for (int i = 0; i < kA; ++i)
#pragma unroll
        for (int j = 0; j < kA; ++j) {
          double acc = 0.0;
#pragma unroll
          for (int p = 0; p < kA; ++p) acc = fma(M[i][p], T[p][j], acc);
          U[i][j] = acc;
        }
      const double rk = 1.0 / (double)k;
#pragma unroll
      for (int i = 0; i < kA; ++i)
#pragma unroll
        for (int j = 0; j < kA; ++j)
          T[i][j] = ((i == j) ? 1.0 : 0.0) + U[i][j] * rk;
    }

#pragma unroll 1
    for (int t = 0; t < kSquarings - 1; ++t) {
      double U[kA][kA];
#pragma unroll
      for (int i = 0; i < kA; ++i)
#pragma unroll
        for (int j = 0; j < kA; ++j) {
          double acc = 0.0;
#pragma unroll
          for (int p = 0; p < kA; ++p) acc = fma(T[i][p], T[p][j], acc);
          U[i][j] = acc;
        }
#pragma unroll
      for (int i = 0; i < kA; ++i)
#pragma unroll
        for (int j = 0; j < kA; ++j) T[i][j] = U[i][j];
    }

    double r0[kA];
#pragma unroll
    for (int j = 0; j < kA; ++j) {
      double acc = 0.0;
#pragma unroll
      for (int p = 0; p < kA; ++p) acc = fma(T[0][p], T[p][j], acc);
      r0[j] = acc;
    }
    rvec = make_float4((float)r0[0], (float)r0[1], (float)r0[2], (float)r0[3]);
  }

  // ---- broadcast across S sites: 16 coalesced float4 stores per lane ----
  float4* o = out + (size_t)v * kS;
#pragma unroll
  for (int k = 0; k < kS / 64; ++k) o[k * 64 + threadIdx.x] = rvec;
}

}  // namespace

extern "C" void kernel_launch(void* const* d_in, const int* in_sizes, int n_in,
                              void* d_out, int out_size, void* d_ws,
                              size_t ws_size, hipStream_t stream) {
  const float* emb  = (const float*)d_in[0];
  // d_in[1] = site_positions_SxC: unused (output is independent of positions)
  const float* W0   = (const float*)d_in[2];
  const float* b0   = (const float*)d_in[3];
  const float* W1   = (const float*)d_in[4];
  const float* b1   = (const float*)d_in[5];
  const float* Wout = (const float*)d_in[6];
  const float* bout = (const float*)d_in[7];

  fused_kernel<<<kV, 64, 0, stream>>>(emb, W0, b0, W1, b1, Wout, bout,
                                      (float4*)d_out);
}

// Round 5
// 12.876 us; speedup vs baseline: 1.8746x; 1.0123x over previous
//
#include <hip/hip_runtime.h>
#include <math.h>

// DenseMLPQMatrixDecoder, fused single kernel.
// Q depends only on v; expm(1000*Q) is (to machine precision) the stationary
// distribution pi of the CTMC whenever all nonzero eigenvalues have
// Re mu < -delta (residual modes ~e^{-1000*delta}).
// Fast path: pi via Markov-tree theorem (diagonal 3x3 cofactors of Q, fp64).
// Gate: Routh-Hurwitz test on the shifted characteristic cubic -- pure
// arithmetic, no transcendentals. Marginal/failing blocks fall back to fp64
// scaling-and-squaring expm (conservative direction = correct).
// Then all 64 lanes broadcast the float4 across S=1024 sites.

namespace {

constexpr int kA = 4;
constexpr int kD = 8;
constexpr int kW = 16;
constexpr int kV = 1024;
constexpr int kS = 1024;
constexpr int kSquarings = 14;   // fallback: 2^14; tau = 1000/16384
constexpr int kTaylorOrder = 8;

__device__ inline double det3(double m00, double m01, double m02,
                              double m10, double m11, double m12,
                              double m20, double m21, double m22) {
  return m00 * (m11 * m22 - m12 * m21) -
         m01 * (m10 * m22 - m12 * m20) +
         m02 * (m10 * m21 - m11 * m20);
}

__global__ __launch_bounds__(64) void fused_kernel(
    const float* __restrict__ emb,
    const float* __restrict__ W0,
    const float* __restrict__ b0,
    const float* __restrict__ W1,
    const float* __restrict__ b1,
    const float* __restrict__ Wout,
    const float* __restrict__ bout,
    float4* __restrict__ out) {
  const int v = blockIdx.x;

  // ---- MLP: D -> W -> W -> A*A (ReLU hidden); uniform across lanes ----
  float x[kD];
#pragma unroll
  for (int d = 0; d < kD; ++d) x[d] = emb[v * kD + d];

  float h0[kW];
#pragma unroll
  for (int j = 0; j < kW; ++j) {
    float acc = b0[j];
#pragma unroll
    for (int d = 0; d < kD; ++d) acc = fmaf(x[d], W0[d * kW + j], acc);
    h0[j] = fmaxf(acc, 0.0f);
  }

  float h1[kW];
#pragma unroll
  for (int j = 0; j < kW; ++j) {
    float acc = b1[j];
#pragma unroll
    for (int k = 0; k < kW; ++k) acc = fmaf(h0[k], W1[k * kW + j], acc);
    h1[j] = fmaxf(acc, 0.0f);
  }

  float l[kA * kA];
#pragma unroll
  for (int j = 0; j < kA * kA; ++j) {
    float acc = bout[j];
#pragma unroll
    for (int k = 0; k < kW; ++k)
      acc = fmaf(h1[k], Wout[k * (kA * kA) + j], acc);
    l[j] = acc;
  }

  // ---- Q = P - I; P = per-row off-diagonal softmax (fp64 entries) ----
  double Q[kA][kA];
#pragma unroll
  for (int i = 0; i < kA; ++i) {
    float m = -3.0e38f;
#pragma unroll
    for (int j = 0; j < kA; ++j)
      if (j != i) m = fmaxf(m, l[i * kA + j]);
    float e[kA];
    float ssum = 0.0f;
#pragma unroll
    for (int j = 0; j < kA; ++j) {
      e[j] = (j == i) ? 0.0f : expf(l[i * kA + j] - m);
      ssum += e[j];
    }
    const float inv = 1.0f / ssum;
#pragma unroll
    for (int j = 0; j < kA; ++j)
      Q[i][j] = (j == i) ? -1.0 : (double)(e[j] * inv);
  }

  // ---- spectral-gap gate, transcendental-free ----
  // Nonzero eigenvalues satisfy f(mu) = mu^3 + 4 mu^2 + e2 mu - e3 = 0
  // (e1 = tr Q = -4 exactly, e4 = det Q = 0 exactly).
  double p2 = 0.0;  // tr(Q^2)
#pragma unroll
  for (int i = 0; i < kA; ++i)
#pragma unroll
    for (int j = 0; j < kA; ++j) p2 = fma(Q[i][j], Q[j][i], p2);

  double Q2[kA][kA];
#pragma unroll
  for (int i = 0; i < kA; ++i)
#pragma unroll
    for (int j = 0; j < kA; ++j) {
      double acc = 0.0;
#pragma unroll
      for (int p = 0; p < kA; ++p) acc = fma(Q[i][p], Q[p][j], acc);
      Q2[i][j] = acc;
    }
  double p3 = 0.0;  // tr(Q^3)
#pragma unroll
  for (int i = 0; i < kA; ++i)
#pragma unroll
    for (int j = 0; j < kA; ++j) p3 = fma(Q2[i][j], Q[j][i], p3);

  // Newton's identities: e2 = (16 - p2)/2;  a0 := -e3 = (32 - 6 p2 - p3)/3.
  const double e2 = (16.0 - p2) * 0.5;
  const double a0 = (32.0 - 6.0 * p2 - p3) * (1.0 / 3.0);
  // Routh-Hurwitz on g(s) = f(s - dlt): all roots of f have Re mu < -dlt
  // iff a2' > 0 (always: 3.91), a1' > 0, a0' > 0, a2'*a1' > a0'.
  constexpr double dlt = 0.03;
  const double a2s = 4.0 - 3.0 * dlt;
  const double a1s = e2 - 8.0 * dlt + 3.0 * dlt * dlt;
  const double a0s = a0 - e2 * dlt + 4.0 * dlt * dlt - dlt * dlt * dlt;
  const bool fast = (a1s > 0.0) && (a0s > 0.0) && (a2s * a1s > a0s);

  float4 rvec;
  if (fast) {
    // ---- fast path: stationary pi via diagonal cofactors (tree theorem) ----
    double c0 = det3(Q[1][1], Q[1][2], Q[1][3],
                     Q[2][1], Q[2][2], Q[2][3],
                     Q[3][1], Q[3][2], Q[3][3]);
    double c1 = det3(Q[0][0], Q[0][2], Q[0][3],
                     Q[2][0], Q[2][2], Q[2][3],
                     Q[3][0], Q[3][2], Q[3][3]);
    double c2 = det3(Q[0][0], Q[0][1], Q[0][3],
                     Q[1][0], Q[1][1], Q[1][3],
                     Q[3][0], Q[3][1], Q[3][3]);
    double c3 = det3(Q[0][0], Q[0][1], Q[0][2],
                     Q[1][0], Q[1][1], Q[1][2],
                     Q[2][0], Q[2][1], Q[2][2]);
    const double inv = 1.0 / (c0 + c1 + c2 + c3);
    rvec = make_float4((float)(c0 * inv), (float)(c1 * inv),
                       (float)(c2 * inv), (float)(c3 * inv));
  } else {
    // ---- fallback: fp64 scaling-and-squaring expm(1000*Q) ----
    const double tau = 1000.0 / (double)(1 << kSquarings);
    double M[kA][kA];
#pragma unroll
    for (int i = 0; i < kA; ++i)
#pragma unroll
      for (int j = 0; j < kA; ++j) M[i][j] = tau * Q[i][j];

    double T[kA][kA];
#pragma unroll
    for (int i = 0; i < kA; ++i)
#pragma unroll
      for (int j = 0; j < kA; ++j) T[i][j] = (i == j) ? 1.0 : 0.0;

#pragma unroll 1
    for (int k = kTaylorOrder; k >= 1; --k) {
      double U[kA][kA];
#pragma unroll
      for (int i = 0; i < kA; ++i)
#pragma unroll
        for (int j = 0; j < kA; ++j) {
          double acc = 0.0;
#pragma unroll
          for (int p = 0; p < kA; ++p) acc = fma(M[i][p], T[p][j], acc);
          U[i][j] = acc;
        }
      const double rk = 1.0 / (double)k;
#pragma unroll
      for (int i = 0; i < kA; ++i)
#pragma unroll
        for (int j = 0; j < kA; ++j)
          T[i][j] = ((i == j) ? 1.0 : 0.0) + U[i][j] * rk;
    }

#pragma unroll 1
    for (int t = 0; t < kSquarings - 1; ++t) {
      double U[kA][kA];
#pragma unroll
      for (int i = 0; i < kA; ++i)
#pragma unroll
        for (int j = 0; j < kA; ++j) {
          double acc = 0.0;
#pragma unroll
          for (int p = 0; p < kA; ++p) acc = fma(T[i][p], T[p][j], acc);
          U[i][j] = acc;
        }
#pragma unroll
      for (int i = 0; i < kA; ++i)
#pragma unroll
        for (int j = 0; j < kA; ++j) T[i][j] = U[i][j];
    }

    double r0[kA];
#pragma unroll
    for (int j = 0; j < kA; ++j) {
      double acc = 0.0;
#pragma unroll
      for (int p = 0; p < kA; ++p) acc = fma(T[0][p], T[p][j], acc);
      r0[j] = acc;
    }
    rvec = make_float4((float)r0[0], (float)r0[1], (float)r0[2], (float)r0[3]);
  }

  // ---- broadcast across S sites: 16 coalesced float4 stores per lane ----
  float4* o = out + (size_t)v * kS;
#pragma unroll
  for (int k = 0; k < kS / 64; ++k) o[k * 64 + threadIdx.x] = rvec;
}

}  // namespace

extern "C" void kernel_launch(void* const* d_in, const int* in_sizes, int n_in,
                              void* d_out, int out_size, void* d_ws,
                              size_t ws_size, hipStream_t stream) {
  const float* emb  = (const float*)d_in[0];
  // d_in[1] = site_positions_SxC: unused (output is independent of positions)
  const float* W0   = (const float*)d_in[2];
  const float* b0   = (const float*)d_in[3];
  const float* W1   = (const float*)d_in[4];
  const float* b1   = (const float*)d_in[5];
  const float* Wout = (const float*)d_in[6];
  const float* bout = (const float*)d_in[7];

  fused_kernel<<<kV, 64, 0, stream>>>(emb, W0, b0, W1, b1, Wout, bout,
                                      (float4*)d_out);
}